// Round 13
// baseline (395.864 us; speedup 1.0000x reference)
//
#include <hip/hip_runtime.h>
#include <hip/hip_bf16.h>
#include <math.h>

#define B_    2
#define N_    9216
#define C_    192
#define HD_   32
#define T_    2304
#define MEM_  8
#define TK_   2312      // T_ + MEM_
#define TKP_  2336      // padded to multiple of 32
#define NPAD_ 24        // TKP_ - TK_
#define MLPH_ 384
#define SCALE_ 0.17677669529663687f
// SCALE * log2(e): q is pre-scaled so attn can use exp2 directly
#define QSCALE_ 0.25504167229218905f
#define EPS_  1e-5f

typedef __bf16 v8bf __attribute__((ext_vector_type(8)));
typedef __bf16 v4bf __attribute__((ext_vector_type(4)));
typedef float  v4f  __attribute__((ext_vector_type(4)));

#define MFMA16(a, b, c) __builtin_amdgcn_mfma_f32_16x16x32_bf16((a), (b), (c), 0, 0, 0)

static __device__ __forceinline__ float gelu_erf(float x) {
    return 0.5f * x * (1.0f + erff(x * 0.70710678118654752f));
}

// ---- pre1: weight transpose (blocks 0..287) || x row-partials (blocks 288..431) ----
__global__ __launch_bounds__(256) void k_pre1(const float* __restrict__ wq,
                       const float* __restrict__ wk,
                       const float* __restrict__ wv, const float* __restrict__ wo,
                       const float* __restrict__ w1, const float* __restrict__ w2,
                       __bf16* __restrict__ wqT, __bf16* __restrict__ wkT,
                       __bf16* __restrict__ wvT, __bf16* __restrict__ woT,
                       __bf16* __restrict__ w1T, __bf16* __restrict__ w2T,
                       const float* __restrict__ x, float* __restrict__ part) {
    __shared__ float tile[32][33];
    int b = blockIdx.x;
    if (b < 288) {
        const float* src; __bf16* dst; int K, Nn, t0;
        if (b < 144)      { int m = b / 36; t0 = b % 36;
                            src = m==0?wq:m==1?wk:m==2?wv:wo;
                            dst = m==0?wqT:m==1?wkT:m==2?wvT:woT; K=192; Nn=192; }
        else if (b < 216) { t0 = b - 144; src = w1; dst = w1T; K=192; Nn=384; }
        else              { t0 = b - 216; src = w2; dst = w2T; K=384; Nn=192; }
        int ntn = Nn / 32;
        int k0 = (t0 / ntn) * 32, n0 = (t0 % ntn) * 32;
        int r = threadIdx.x >> 5, c = threadIdx.x & 31;
#pragma unroll
        for (int i = 0; i < 4; ++i)
            tile[r + i * 8][c] = src[(size_t)(k0 + r + i * 8) * Nn + n0 + c];
        __syncthreads();
#pragma unroll
        for (int i = 0; i < 4; ++i)
            dst[(size_t)(n0 + r + i * 8) * K + k0 + c] = (__bf16)tile[c][r + i * 8];
    } else {
        int j = threadIdx.x;
        if (j < 192) {
            const float* p = x + (size_t)(b - 288) * 128 * C_;
            float s = 0.f;
            for (int r = 0; r < 128; ++r) s += p[r * C_ + j];
            part[(b - 288) * C_ + j] = s;
        }
    }
}

// ------- pre2: kvproj (blocks 0..143) || meanfin (block 144) -------
__global__ __launch_bounds__(256) void k_pre2(const float* __restrict__ x,
        const float* __restrict__ lnw, const float* __restrict__ lnb,
        const __bf16* __restrict__ wkT, const float* __restrict__ bk,
        const __bf16* __restrict__ wvT, const float* __restrict__ bv,
        __bf16* __restrict__ kcat, __bf16* __restrict__ vTr,
        const float* __restrict__ part, float* __restrict__ meanx) {
    if (blockIdx.x == 144) {
        int j = threadIdx.x;
        if (j < 192) {
            float s = 0.f;
            for (int i = 0; i < 144; ++i) s += part[i * C_ + j];
            meanx[j] = s * (1.0f / 18432.0f);
        }
        return;
    }
    __shared__ float  Of[32][196];
    __shared__ __bf16 Abf[32][200];
    __shared__ float  mu_s[32], rs_s[32];
    int tid = threadIdx.x;
    int w = tid >> 6, lane = tid & 63, qi = lane & 15, g = lane >> 4;
    int p0 = blockIdx.x * 32;
    int bbb = p0 / T_, tbase = p0 % T_;

    for (int e = tid; e < 32 * 48; e += 256) {
        int r = e / 48, c4 = e % 48;
        int t = tbase + r;
        int h2 = t / 48, w2c = t % 48;
        const float* s0 = x + ((size_t)bbb * N_ + (size_t)(2 * h2) * 96 + 2 * w2c) * C_ + c4 * 4;
        float4 u0 = *(const float4*)(s0);
        float4 u1 = *(const float4*)(s0 + C_);
        float4 u2 = *(const float4*)(s0 + 96 * C_);
        float4 u3 = *(const float4*)(s0 + 96 * C_ + C_);
        float4 a;
        a.x = 0.25f * (u0.x + u1.x + u2.x + u3.x);
        a.y = 0.25f * (u0.y + u1.y + u2.y + u3.y);
        a.z = 0.25f * (u0.z + u1.z + u2.z + u3.z);
        a.w = 0.25f * (u0.w + u1.w + u2.w + u3.w);
        *(float4*)&Of[r][c4 * 4] = a;
    }
    __syncthreads();
    {
        int r = tid >> 3, part8 = tid & 7;
        float s = 0.f, ss = 0.f;
        for (int i = 0; i < 24; ++i) { float a = Of[r][part8 * 24 + i]; s += a; ss += a * a; }
        s += __shfl_xor(s, 1); ss += __shfl_xor(ss, 1);
        s += __shfl_xor(s, 2); ss += __shfl_xor(ss, 2);
        s += __shfl_xor(s, 4); ss += __shfl_xor(ss, 4);
        if (part8 == 0) {
            float m = s * (1.f / C_);
            float var = ss * (1.f / C_) - m * m;
            mu_s[r] = m; rs_s[r] = rsqrtf(var + EPS_);
        }
    }
    __syncthreads();
    {
        int r = tid >> 3, part8 = tid & 7;
        float m = mu_s[r], rv = rs_s[r];
        for (int i = 0; i < 24; ++i) {
            int c = part8 * 24 + i;
            Abf[r][c] = (__bf16)((Of[r][c] - m) * rv * lnw[c] + lnb[c]);
        }
    }
    __syncthreads();

    v4f ak[2][3], av[2][3];
#pragma unroll
    for (int m = 0; m < 2; ++m)
#pragma unroll
        for (int n = 0; n < 3; ++n) { ak[m][n] = (v4f){0.f,0.f,0.f,0.f}; av[m][n] = (v4f){0.f,0.f,0.f,0.f}; }
#pragma unroll
    for (int kk = 0; kk < 6; ++kk) {
        v8bf a0 = *(const v8bf*)&Abf[qi][kk * 32 + g * 8];
        v8bf a1 = *(const v8bf*)&Abf[16 + qi][kk * 32 + g * 8];
#pragma unroll
        for (int n = 0; n < 3; ++n) {
            int col = w * 48 + n * 16 + qi;
            v8bf bk8 = *(const v8bf*)(wkT + (size_t)col * C_ + kk * 32 + g * 8);
            v8bf bv8 = *(const v8bf*)(wvT + (size_t)col * C_ + kk * 32 + g * 8);
            ak[0][n] = MFMA16(a0, bk8, ak[0][n]);
            ak[1][n] = MFMA16(a1, bk8, ak[1][n]);
            av[0][n] = MFMA16(a0, bv8, av[0][n]);
            av[1][n] = MFMA16(a1, bv8, av[1][n]);
        }
    }
#pragma unroll
    for (int n = 0; n < 3; ++n) {
        int col = w * 48 + n * 16 + qi;
        float bkc = bk[col], bvc = bv[col];
        int hh = col >> 5, dd = col & 31;
        size_t vrow = ((size_t)(bbb * 6 + hh) * HD_ + dd) * TKP_;
#pragma unroll
        for (int m = 0; m < 2; ++m) {
            v4bf vv;
#pragma unroll
            for (int r = 0; r < 4; ++r) {
                int t = tbase + m * 16 + g * 4 + r;
                size_t row = (size_t)bbb * TKP_ + t;
                kcat[row * C_ + col] = (__bf16)(ak[m][n][r] + bkc);
                vv[r] = (__bf16)(av[m][n][r] + bvc);
            }
            // slot-permuted: t32 = m*16+g*4+r  ->  slot = g*8 + m*4 + r
            *(v4bf*)(vTr + vrow + tbase + g * 8 + m * 4) = vv;
        }
    }
}

// ---- pre3: qproj (blocks 0..575) || mempart (blocks 576..671) ----
__global__ __launch_bounds__(256) void k_pre3(const float* __restrict__ x,
        const float* __restrict__ lnw, const float* __restrict__ lnb,
        const __bf16* __restrict__ wqT, const float* __restrict__ bq,
        __bf16* __restrict__ q,
        const __bf16* __restrict__ kcat, const __bf16* __restrict__ vTr,
        float* __restrict__ kp, float* __restrict__ vp) {
    if (blockIdx.x >= 576) {
        int e = blockIdx.x - 576;              // 0..95
        int m = e / 12, ch = e % 12;
        int j = threadIdx.x;
        if (j < 192) {
            int hh = j >> 5, dd = j & 31;
            float sk = 0.f, sv = 0.f;
            for (int bb = 0; bb < 2; ++bb) {
                const __bf16* kpp = kcat + ((size_t)bb * TKP_ + m * 288 + ch * 24) * C_ + j;
                for (int t = 0; t < 24; ++t) sk += (float)kpp[t * C_];
                const __bf16* p = vTr + ((size_t)(bb * 6 + hh) * HD_ + dd) * TKP_ + m * 288 + ch * 24;
                for (int t = 0; t < 24; t += 8) {
                    v8bf v = *(const v8bf*)(p + t);
#pragma unroll
                    for (int u = 0; u < 8; ++u) sv += (float)v[u];
                }
            }
            kp[(m * 12 + ch) * C_ + j] = sk;
            vp[(m * 12 + ch) * C_ + j] = sv;
        }
        return;
    }
    __shared__ float  Of[32][196];
    __shared__ __bf16 Abf[32][200];
    __shared__ float  mu_s[32], rs_s[32];
    int tid = threadIdx.x;
    int w = tid >> 6, lane = tid & 63, qi = lane & 15, g = lane >> 4;
    size_t row0 = (size_t)blockIdx.x * 32;

    for (int e = tid; e < 32 * 48; e += 256) {
        int r = e / 48, c4 = e % 48;
        *(float4*)&Of[r][c4 * 4] = *(const float4*)(x + (row0 + r) * C_ + c4 * 4);
    }
    __syncthreads();
    {
        int r = tid >> 3, part8 = tid & 7;
        float s = 0.f, ss = 0.f;
        for (int i = 0; i < 24; ++i) { float a = Of[r][part8 * 24 + i]; s += a; ss += a * a; }
        s += __shfl_xor(s, 1); ss += __shfl_xor(ss, 1);
        s += __shfl_xor(s, 2); ss += __shfl_xor(ss, 2);
        s += __shfl_xor(s, 4); ss += __shfl_xor(ss, 4);
        if (part8 == 0) {
            float m = s * (1.f / C_);
            float var = ss * (1.f / C_) - m * m;
            mu_s[r] = m; rs_s[r] = rsqrtf(var + EPS_);
        }
    }
    __syncthreads();
    {
        int r = tid >> 3, part8 = tid & 7;
        float m = mu_s[r], rv = rs_s[r];
        for (int i = 0; i < 24; ++i) {
            int c = part8 * 24 + i;
            Abf[r][c] = (__bf16)((Of[r][c] - m) * rv * lnw[c] + lnb[c]);
        }
    }
    __syncthreads();

    v4f acc[2][3];
#pragma unroll
    for (int m = 0; m < 2; ++m)
#pragma unroll
        for (int n = 0; n < 3; ++n) acc[m][n] = (v4f){0.f, 0.f, 0.f, 0.f};
#pragma unroll
    for (int kk = 0; kk < 6; ++kk) {
        v8bf a0 = *(const v8bf*)&Abf[qi][kk * 32 + g * 8];
        v8bf a1 = *(const v8bf*)&Abf[16 + qi][kk * 32 + g * 8];
#pragma unroll
        for (int n = 0; n < 3; ++n) {
            v8bf bfr = *(const v8bf*)(wqT + (size_t)(w * 48 + n * 16 + qi) * C_ + kk * 32 + g * 8);
            acc[0][n] = MFMA16(a0, bfr, acc[0][n]);
            acc[1][n] = MFMA16(a1, bfr, acc[1][n]);
        }
    }
#pragma unroll
    for (int n = 0; n < 3; ++n) {
        int col = w * 48 + n * 16 + qi;
        float bb = bq[col];
#pragma unroll
        for (int m = 0; m < 2; ++m)
#pragma unroll
            for (int r = 0; r < 4; ++r)
                q[(row0 + m * 16 + g * 4 + r) * C_ + col] = (__bf16)((acc[m][n][r] + bb) * QSCALE_);
    }
}

// ------- EMA memory rows (blocks 0..7) + zero pad slots (blocks 8..31) -------
__global__ void k_memfin(const float* __restrict__ meanx,
                         const float* __restrict__ kp, const float* __restrict__ vp,
                         __bf16* __restrict__ kcat, __bf16* __restrict__ vTr) {
    int m = blockIdx.x, j = threadIdx.x;
    int hh = j >> 5, dd = j & 31;
    if (m < 8) {
        float sk = 0.f, sv = 0.f;
        for (int ch = 0; ch < 12; ++ch) {
            sk += kp[(m * 12 + ch) * C_ + j];
            sv += vp[(m * 12 + ch) * C_ + j];
        }
        float mk = 0.99f * meanx[j] + 0.01f * sk * (1.0f / 576.0f);
        float mv = sv * (0.01f / 576.0f);
        for (int bb = 0; bb < 2; ++bb)
            kcat[((size_t)bb * TKP_ + T_ + m) * C_ + j] = (__bf16)mk;
        int slot = (m >> 2) * 8 + (m & 3);     // t32 = m (<16)
        for (int bb = 0; bb < 2; ++bb)
            vTr[((size_t)(bb * 6 + hh) * HD_ + dd) * TKP_ + T_ + slot] = (__bf16)mv;
    } else {
        int t32 = m;                           // 8..31 within block at base T_
        int slot = (t32 < 16) ? ((t32 >> 2) * 8 + (t32 & 3))
                              : (((t32 >> 2) - 4) * 8 + 4 + (t32 & 3));
        for (int bb = 0; bb < 2; ++bb) {
            kcat[((size_t)bb * TKP_ + TK_ + (m - 8)) * C_ + j] = (__bf16)0.f;
            vTr[((size_t)(bb * 6 + hh) * HD_ + dd) * TKP_ + T_ + slot] = (__bf16)0.f;
        }
    }
}

// ------- MFMA attention: 1-wave blocks, 64 q/wave (4 tiles), 4-way key split -------
// S^T = mfma(K,Q); p = raw v_exp_f32(s); PV B-frag = own lane's p (V slot-permuted);
// ps as scalar f32 adds (end-of-loop shfl reduce) to stay under the 64-VGPR cliff.
__global__ __launch_bounds__(64, 8) void k_attn(const __bf16* __restrict__ q,
                                                const __bf16* __restrict__ kc,
                                                const __bf16* __restrict__ vt,
                                                __bf16* __restrict__ po,
                                                float* __restrict__ psb) {
    int lane = threadIdx.x & 63, g = lane >> 4, qi = lane & 15;
    int bs = blockIdx.z;                       // bb*4 + split
    int bb = bs >> 2, sp = bs & 3;
    int h = blockIdx.y;
    int qt = blockIdx.x * 64;
    int kv_lo = sp * 576;
    int kv_hi = (sp == 3) ? TKP_ : kv_lo + 576;
    const size_t BNC = (size_t)B_ * N_ * C_;

    v8bf qf[4];
#pragma unroll
    for (int t = 0; t < 4; ++t)
        qf[t] = *(const v8bf*)(q + ((size_t)bb * N_ + qt + t * 16 + qi) * C_ + h * HD_ + g * 8);

    v4f o0[4], o1[4];
    float ps[4];
#pragma unroll
    for (int t = 0; t < 4; ++t) {
        o0[t] = (v4f){0.f,0.f,0.f,0.f};
        o1[t] = (v4f){0.f,0.f,0.f,0.f};
        ps[t] = 0.f;
    }

    const __bf16* kbase = kc + ((size_t)bb * TKP_ + qi) * C_ + h * HD_ + g * 8;
    const __bf16* vb0 = vt + ((size_t)((bb * 6 + h) * HD_) + qi) * TKP_ + g * 8;
    const __bf16* vb1 = vb0 + (size_t)16 * TKP_;

    for (int kv0 = kv_lo; kv0 < kv_hi; kv0 += 32) {
        v8bf kf0 = *(const v8bf*)(kbase + (size_t)kv0 * C_);
        v8bf kf1 = *(const v8bf*)(kbase + (size_t)(kv0 + 16) * C_);
        v8bf va0 = *(const v8bf*)(vb0 + kv0);
        v8bf va1 = *(const v8bf*)(vb1 + kv0);
        v4f z = {0.f,0.f,0.f,0.f};
#pragma unroll
        for (int t = 0; t < 4; ++t) {
            v4f s0 = MFMA16(kf0, qf[t], z);
            v4f s1 = MFMA16(kf1, qf[t], z);
            v8bf pb;                            // slots j<4: keys g*4+j; j>=4: 16+g*4+j-4
#pragma unroll
            for (int r = 0; r < 4; ++r) {
                float e0 = __builtin_amdgcn_exp2f(s0[r]);
                float e1 = __builtin_amdgcn_exp2f(s1[r]);
                ps[t] += e0 + e1;
                pb[r]     = (__bf16)e0;
                pb[4 + r] = (__bf16)e1;
            }
            o0[t] = MFMA16(va0, pb, o0[t]);
            o1[t] = MFMA16(va1, pb, o1[t]);
        }
    }

    __bf16* pbase = po + (size_t)sp * BNC;
#pragma unroll
    for (int t = 0; t < 4; ++t) {
        ps[t] += __shfl_xor(ps[t], 16);
        ps[t] += __shfl_xor(ps[t], 32);
        __bf16* orow = pbase + ((size_t)bb * N_ + qt + t * 16 + qi) * C_ + h * HD_;
        v4bf a, b;
#pragma unroll
        for (int r = 0; r < 4; ++r) { a[r] = (__bf16)o0[t][r]; b[r] = (__bf16)o1[t][r]; }
        *(v4bf*)(orow + g * 4)      = a;
        *(v4bf*)(orow + 16 + g * 4) = b;
    }
    if (lane < 16) {                           // all g-lanes now hold full sums
#pragma unroll
        for (int t = 0; t < 4; ++t)
            psb[((size_t)bs * 6 + h) * N_ + qt + t * 16 + qi] = ps[t];
    }
}

// ---- MFMA post (merge fused): ao = Σpo/ps -> @wo+bo -> reg-LN -> MLP -> +res ----
__global__ __launch_bounds__(256) void k_post(const __bf16* __restrict__ po,
        const float* __restrict__ psb,
        const __bf16* __restrict__ woT, const float* __restrict__ bo,
        const float* __restrict__ ln2w, const float* __restrict__ ln2b,
        const __bf16* __restrict__ w1T, const float* __restrict__ b1,
        const __bf16* __restrict__ w2T, const float* __restrict__ b2,
        float* __restrict__ out) {
    __shared__ __bf16 Abf[32][200];
    __shared__ __bf16 H[32][392];
    __shared__ float  partLN[4][32][2];
    __shared__ float  mu_s[32], rs_s[32];
    __shared__ float  inv_s[32][6];
    int tid = threadIdx.x;
    int w = tid >> 6, lane = tid & 63, qi = lane & 15, g = lane >> 4;
    size_t row0 = (size_t)blockIdx.x * 32;
    const size_t BNC = (size_t)B_ * N_ * C_;

    // per-(row,head) denominators: sum of 4 split partials - pad correction
    if (tid < 192) {
        int r = tid / 6, h = tid % 6;
        size_t n = row0 + r;
        int bb = (n >= N_) ? 1 : 0;
        int nn = (int)(n - (size_t)bb * N_);
        float s = -(float)NPAD_;
#pragma unroll
        for (int sp = 0; sp < 4; ++sp)
            s += psb[((size_t)(bb * 4 + sp) * 6 + h) * N_ + nn];
        inv_s[r][h] = 1.f / s;
    }
    __syncthreads();

    // merge 4 bf16 partials -> normalized bf16 A tile
    for (int e = tid; e < 32 * 48; e += 256) {
        int r = e / 48, c4 = e % 48;
        float iv = inv_s[r][c4 >> 3];
        size_t n = row0 + r;
        float acc[4] = {0.f, 0.f, 0.f, 0.f};
#pragma unroll
        for (int sp = 0; sp < 4; ++sp) {
            v4bf v = *(const v4bf*)(po + (size_t)sp * BNC + n * C_ + c4 * 4);
#pragma unroll
            for (int u = 0; u < 4; ++u) acc[u] += (float)v[u];
        }
        v4bf pbf;
#pragma unroll
        for (int u = 0; u < 4; ++u) pbf[u] = (__bf16)(acc[u] * iv);
        *(v4bf*)&Abf[r][c4 * 4] = pbf;
    }
    __syncthreads();

    // GEMM1: o = A @ wo + bo (kept in regs for residual + LN)
    v4f acc1[2][3];
#pragma unroll
    for (int m = 0; m < 2; ++m)
#pragma unroll
        for (int n = 0; n < 3; ++n) acc1[m][n] = (v4f){0.f,0.f,0.f,0.f};
#pragma unroll
    for (int kk = 0; kk < 6; ++kk) {
        v8bf a0 = *(const v8bf*)&Abf[qi][kk * 32 + g * 8];
        v8bf a1 = *(const v8bf*)&Abf[16 + qi][kk * 32 + g * 8];
#pragma unroll
        for (int n = 0; n < 3; ++n) {
            v8bf bfr = *(const v8bf*)(woT + (size_t)(w * 48 + n * 16 + qi) * C_ + kk * 32 + g * 8);
            acc1[0][n] = MFMA16(a0, bfr, acc1[0][n]);
            acc1[1][n] = MFMA16(a1, bfr, acc1[1][n]);
        }
    }
#pragma unroll
    for (int n = 0; n < 3; ++n) {
        float bb = bo[w * 48 + n * 16 + qi];
#pragma unroll
        for (int m = 0; m < 2; ++m)
#pragma unroll
            for (int r = 0; r < 4; ++r) acc1[m][n][r] += bb;
    }

    // register LN: per-row stats via qi-shuffles + 1KB cross-wave partials
    {
        float sr[2][4], qr[2][4];
#pragma unroll
        for (int m = 0; m < 2; ++m)
#pragma unroll
            for (int r = 0; r < 4; ++r) {
                float s = acc1[m][0][r] + acc1[m][1][r] + acc1[m][2][r];
                float q2 = acc1[m][0][r] * acc1[m][0][r] + acc1[m][1][r] * acc1[m][1][r]
                         + acc1[m][2][r] * acc1[m][2][r];
                s += __shfl_xor(s, 1); q2 += __shfl_xor(q2, 1);
                s += __shfl_xor(s, 2); q2 += __shfl_xor(q2, 2);
                s += __shfl_xor(s, 4); q2 += __shfl_xor(q2, 4);
                s += __shfl_xor(s, 8); q2 += __shfl_xor(q2, 8);
                sr[m][r] = s; qr[m][r] = q2;
            }
        if (qi == 0) {
#pragma unroll
            for (int m = 0; m < 2; ++m)
#pragma unroll
                for (int r = 0; r < 4; ++r) {
                    partLN[w][m * 16 + g * 4 + r][0] = sr[m][r];
                    partLN[w][m * 16 + g * 4 + r][1] = qr[m][r];
                }
        }
    }
    __syncthreads();
    if (tid < 32) {
        float s  = partLN[0][tid][0] + partLN[1][tid][0] + partLN[2][tid][0] + partLN[3][tid][0];
        float q2 = partLN[0][tid][1] + partLN[1][tid][1] + partLN[2][tid][1] + partLN[3][tid][1];
        float mm = s * (1.f / C_);
        float var = q2 * (1.f / C_) - mm * mm;
        mu_s[tid] = mm; rs_s[tid] = rsqrtf(var + EPS_);
    }
    __syncthreads();
    // write LN'd values to Abf straight from registers
#pragma unroll
    for (int n = 0; n < 3; ++n) {
        int col = w * 48 + n * 16 + qi;
        float lw = ln2w[col], lb = ln2b[col];
#pragma unroll
        for (int m = 0; m < 2; ++m)
#pragma unroll
            for (int r = 0; r < 4; ++r) {
                int row = m * 16 + g * 4 + r;
                Abf[row][col] = (__bf16)((acc1[m][n][r] - mu_s[row]) * rs_s[row] * lw + lb);
            }
    }
    __syncthreads();

    // GEMM2: g = h @ w1 + b1, GELU -> H
    v4f acc2[2][6];
#pragma unroll
    for (int m = 0; m < 2; ++m)
#pragma unroll
        for (int n = 0; n < 6; ++n) acc2[m][n] = (v4f){0.f,0.f,0.f,0.f};
#pragma unroll
    for (int kk = 0; kk < 6; ++kk) {
        v8bf a0 = *(const v8bf*)&Abf[qi][kk * 32 + g * 8];
        v8bf a1 = *(const v8bf*)&Abf[16 + qi][kk * 32 + g * 8];
#pragma unroll
        for (int n = 0; n < 6; ++n) {
            v8bf bfr = *(const v8bf*)(w1T + (size_t)(w * 96 + n * 16 + qi) * C_ + kk * 32 + g * 8);
            acc2[0][n] = MFMA16(a0, bfr, acc2[0][n]);
            acc2[1][n] = MFMA16(a1, bfr, acc2[1][n]);
        }
    }
#pragma unroll
    for (int n = 0; n < 6; ++n) {
        int col = w * 96 + n * 16 + qi;
        float bb = b1[col];
#pragma unroll
        for (int m = 0; m < 2; ++m)
#pragma unroll
            for (int r = 0; r < 4; ++r)
                H[m * 16 + g * 4 + r][col] = (__bf16)gelu_erf(acc2[m][n][r] + bb);
    }
    __syncthreads();

    // GEMM3: f = g @ w2 + b2; out = o + f
    v4f acc3[2][3];
#pragma unroll
    for (int m = 0; m < 2; ++m)
#pragma unroll
        for (int n = 0; n < 3; ++n) acc3[m][n] = (v4f){0.f,0.f,0.f,0.f};
#pragma unroll
    for (int kk = 0; kk < 12; ++kk) {
        v8bf a0 = *(const v8bf*)&H[qi][kk * 32 + g * 8];
        v8bf a1 = *(const v8bf*)&H[16 + qi][kk * 32 + g * 8];
#pragma unroll
        for (int n = 0; n < 3; ++n) {
            v8bf bfr = *(const v8bf*)(w2T + (size_t)(w * 48 + n * 16 + qi) * MLPH_ + kk * 32 + g * 8);
            acc3[0][n] = MFMA16(a0, bfr, acc3[0][n]);
            acc3[1][n] = MFMA16(a1, bfr, acc3[1][n]);
        }
    }
#pragma unroll
    for (int n = 0; n < 3; ++n) {
        int col = w * 48 + n * 16 + qi;
        float bb = b2[col];
#pragma unroll
        for (int m = 0; m < 2; ++m)
#pragma unroll
            for (int r = 0; r < 4; ++r)
                out[(row0 + m * 16 + g * 4 + r) * C_ + col] = acc1[m][n][r] + acc3[m][n][r] + bb;
    }
}

extern "C" void kernel_launch(void* const* d_in, const int* in_sizes, int n_in,
                              void* d_out, int out_size, void* d_ws, size_t ws_size,
                              hipStream_t stream) {
    const float* x    = (const float*)d_in[0];
    const float* lnqw = (const float*)d_in[1];
    const float* lnqb = (const float*)d_in[2];
    const float* lnkw = (const float*)d_in[3];
    const float* lnkb = (const float*)d_in[4];
    const float* wq   = (const float*)d_in[5];
    const float* bq   = (const float*)d_in[6];
    const float* wk   = (const float*)d_in[7];
    const float* bk   = (const float*)d_in[8];
    const float* wv   = (const float*)d_in[9];
    const float* bv   = (const float*)d_in[10];
    const float* wo   = (const float*)d_in[11];
    const float* bo   = (const float*)d_in[12];
    const float* ln2w = (const float*)d_in[13];
    const float* ln2b = (const float*)d_in[14];
    const float* w1   = (const float*)d_in[15];
    const float* b1   = (const float*)d_in[16];
    const float* w2   = (const float*)d_in[17];
    const float* b2   = (const float*)d_in[18];

    char* w0 = (char*)d_ws;
    const size_t QB  = (size_t)B_ * N_ * C_ * 2;       // 7,077,888
    const size_t KVB = (size_t)B_ * TKP_ * C_ * 2;     // 1,794,048
    const size_t POB = (size_t)4 * B_ * N_ * C_ * 2;   // 28,311,552 (4 bf16 splits)
    __bf16* qb  = (__bf16*)(w0);
    __bf16* kcb = (__bf16*)(w0 + QB);
    __bf16* vtr = (__bf16*)(w0 + QB + KVB);
    __bf16* po  = (__bf16*)(w0 + QB + 2 * KVB);
    float*  psb = (float*) (w0 + QB + 2 * KVB + POB);    // 8*6*N f32
    float*  kp    = psb + (size_t)8 * 6 * N_;            // 96*192
    float*  vp    = kp + 96 * C_;                        // 96*192
    float*  part  = vp + 96 * C_;                        // 144*192
    float*  meanx = part + 144 * C_;
    char* wbase = (char*)(meanx + 192 + 32);
    wbase = (char*)(((uintptr_t)wbase + 255) & ~(uintptr_t)255);
    __bf16* wqT = (__bf16*)(wbase);
    __bf16* wkT = wqT + 36864;
    __bf16* wvT = wkT + 36864;
    __bf16* woT = wvT + 36864;
    __bf16* w1T = woT + 36864;
    __bf16* w2T = w1T + 73728;

    hipLaunchKernelGGL(k_pre1, dim3(432), dim3(256), 0, stream,
                       wq, wk, wv, wo, w1, w2, wqT, wkT, wvT, woT, w1T, w2T, x, part);
    hipLaunchKernelGGL(k_pre2, dim3(145), dim3(256), 0, stream,
                       x, lnkw, lnkb, wkT, bk, wvT, bv, kcb, vtr, part, meanx);
    hipLaunchKernelGGL(k_pre3, dim3(672), dim3(256), 0, stream,
                       x, lnqw, lnqb, wqT, bq, qb, kcb, vtr, kp, vp);
    hipLaunchKernelGGL(k_memfin, dim3(32), dim3(192), 0, stream, meanx, kp, vp, kcb, vtr);
    hipLaunchKernelGGL(k_attn, dim3(144, 6, 8), dim3(64), 0, stream,
                       qb, kcb, vtr, po, psb);
    hipLaunchKernelGGL(k_post, dim3(576), dim3(256), 0, stream,
                       po, psb, woT, bo, ln2w, ln2b, w1T, b1, w2T, b2, (float*)d_out);
}

// Round 14
// 141.299 us; speedup vs baseline: 2.8016x; 2.8016x over previous
//
#include <hip/hip_runtime.h>
#include <hip/hip_bf16.h>
#include <math.h>

#define B_    2
#define N_    9216
#define C_    192
#define HD_   32
#define T_    2304
#define MEM_  8
#define TK_   2312      // T_ + MEM_
#define TKP_  2336      // padded to multiple of 32
#define NPAD_ 24        // TKP_ - TK_
#define MLPH_ 384
#define SCALE_ 0.17677669529663687f
// SCALE * log2(e): q is pre-scaled so attn can use exp2 directly
#define QSCALE_ 0.25504167229218905f
#define EPS_  1e-5f

typedef __bf16 v8bf __attribute__((ext_vector_type(8)));
typedef __bf16 v4bf __attribute__((ext_vector_type(4)));
typedef float  v4f  __attribute__((ext_vector_type(4)));

#define MFMA16(a, b, c) __builtin_amdgcn_mfma_f32_16x16x32_bf16((a), (b), (c), 0, 0, 0)

static __device__ __forceinline__ float gelu_erf(float x) {
    return 0.5f * x * (1.0f + erff(x * 0.70710678118654752f));
}

// ---- pre1: weight transpose (blocks 0..287) || x row-partials (blocks 288..431) ----
__global__ __launch_bounds__(256) void k_pre1(const float* __restrict__ wq,
                       const float* __restrict__ wk,
                       const float* __restrict__ wv, const float* __restrict__ wo,
                       const float* __restrict__ w1, const float* __restrict__ w2,
                       __bf16* __restrict__ wqT, __bf16* __restrict__ wkT,
                       __bf16* __restrict__ wvT, __bf16* __restrict__ woT,
                       __bf16* __restrict__ w1T, __bf16* __restrict__ w2T,
                       const float* __restrict__ x, float* __restrict__ part) {
    __shared__ float tile[32][33];
    int b = blockIdx.x;
    if (b < 288) {
        const float* src; __bf16* dst; int K, Nn, t0;
        if (b < 144)      { int m = b / 36; t0 = b % 36;
                            src = m==0?wq:m==1?wk:m==2?wv:wo;
                            dst = m==0?wqT:m==1?wkT:m==2?wvT:woT; K=192; Nn=192; }
        else if (b < 216) { t0 = b - 144; src = w1; dst = w1T; K=192; Nn=384; }
        else              { t0 = b - 216; src = w2; dst = w2T; K=384; Nn=192; }
        int ntn = Nn / 32;
        int k0 = (t0 / ntn) * 32, n0 = (t0 % ntn) * 32;
        int r = threadIdx.x >> 5, c = threadIdx.x & 31;
#pragma unroll
        for (int i = 0; i < 4; ++i)
            tile[r + i * 8][c] = src[(size_t)(k0 + r + i * 8) * Nn + n0 + c];
        __syncthreads();
#pragma unroll
        for (int i = 0; i < 4; ++i)
            dst[(size_t)(n0 + r + i * 8) * K + k0 + c] = (__bf16)tile[c][r + i * 8];
    } else {
        int j = threadIdx.x;
        if (j < 192) {
            const float* p = x + (size_t)(b - 288) * 128 * C_;
            float s = 0.f;
            for (int r = 0; r < 128; ++r) s += p[r * C_ + j];
            part[(b - 288) * C_ + j] = s;
        }
    }
}

// ------- pre2: kvproj (blocks 0..143) || meanfin (block 144) -------
__global__ __launch_bounds__(256) void k_pre2(const float* __restrict__ x,
        const float* __restrict__ lnw, const float* __restrict__ lnb,
        const __bf16* __restrict__ wkT, const float* __restrict__ bk,
        const __bf16* __restrict__ wvT, const float* __restrict__ bv,
        __bf16* __restrict__ kcat, __bf16* __restrict__ vTr,
        const float* __restrict__ part, float* __restrict__ meanx) {
    if (blockIdx.x == 144) {
        int j = threadIdx.x;
        if (j < 192) {
            float s = 0.f;
            for (int i = 0; i < 144; ++i) s += part[i * C_ + j];
            meanx[j] = s * (1.0f / 18432.0f);
        }
        return;
    }
    __shared__ float  Of[32][196];
    __shared__ __bf16 Abf[32][200];
    __shared__ float  mu_s[32], rs_s[32];
    int tid = threadIdx.x;
    int w = tid >> 6, lane = tid & 63, qi = lane & 15, g = lane >> 4;
    int p0 = blockIdx.x * 32;
    int bbb = p0 / T_, tbase = p0 % T_;

    for (int e = tid; e < 32 * 48; e += 256) {
        int r = e / 48, c4 = e % 48;
        int t = tbase + r;
        int h2 = t / 48, w2c = t % 48;
        const float* s0 = x + ((size_t)bbb * N_ + (size_t)(2 * h2) * 96 + 2 * w2c) * C_ + c4 * 4;
        float4 u0 = *(const float4*)(s0);
        float4 u1 = *(const float4*)(s0 + C_);
        float4 u2 = *(const float4*)(s0 + 96 * C_);
        float4 u3 = *(const float4*)(s0 + 96 * C_ + C_);
        float4 a;
        a.x = 0.25f * (u0.x + u1.x + u2.x + u3.x);
        a.y = 0.25f * (u0.y + u1.y + u2.y + u3.y);
        a.z = 0.25f * (u0.z + u1.z + u2.z + u3.z);
        a.w = 0.25f * (u0.w + u1.w + u2.w + u3.w);
        *(float4*)&Of[r][c4 * 4] = a;
    }
    __syncthreads();
    {
        int r = tid >> 3, part8 = tid & 7;
        float s = 0.f, ss = 0.f;
        for (int i = 0; i < 24; ++i) { float a = Of[r][part8 * 24 + i]; s += a; ss += a * a; }
        s += __shfl_xor(s, 1); ss += __shfl_xor(ss, 1);
        s += __shfl_xor(s, 2); ss += __shfl_xor(ss, 2);
        s += __shfl_xor(s, 4); ss += __shfl_xor(ss, 4);
        if (part8 == 0) {
            float m = s * (1.f / C_);
            float var = ss * (1.f / C_) - m * m;
            mu_s[r] = m; rs_s[r] = rsqrtf(var + EPS_);
        }
    }
    __syncthreads();
    {
        int r = tid >> 3, part8 = tid & 7;
        float m = mu_s[r], rv = rs_s[r];
        for (int i = 0; i < 24; ++i) {
            int c = part8 * 24 + i;
            Abf[r][c] = (__bf16)((Of[r][c] - m) * rv * lnw[c] + lnb[c]);
        }
    }
    __syncthreads();

    v4f ak[2][3], av[2][3];
#pragma unroll
    for (int m = 0; m < 2; ++m)
#pragma unroll
        for (int n = 0; n < 3; ++n) { ak[m][n] = (v4f){0.f,0.f,0.f,0.f}; av[m][n] = (v4f){0.f,0.f,0.f,0.f}; }
#pragma unroll
    for (int kk = 0; kk < 6; ++kk) {
        v8bf a0 = *(const v8bf*)&Abf[qi][kk * 32 + g * 8];
        v8bf a1 = *(const v8bf*)&Abf[16 + qi][kk * 32 + g * 8];
#pragma unroll
        for (int n = 0; n < 3; ++n) {
            int col = w * 48 + n * 16 + qi;
            v8bf bk8 = *(const v8bf*)(wkT + (size_t)col * C_ + kk * 32 + g * 8);
            v8bf bv8 = *(const v8bf*)(wvT + (size_t)col * C_ + kk * 32 + g * 8);
            ak[0][n] = MFMA16(a0, bk8, ak[0][n]);
            ak[1][n] = MFMA16(a1, bk8, ak[1][n]);
            av[0][n] = MFMA16(a0, bv8, av[0][n]);
            av[1][n] = MFMA16(a1, bv8, av[1][n]);
        }
    }
#pragma unroll
    for (int n = 0; n < 3; ++n) {
        int col = w * 48 + n * 16 + qi;
        float bkc = bk[col], bvc = bv[col];
        int hh = col >> 5, dd = col & 31;
        size_t vrow = ((size_t)(bbb * 6 + hh) * HD_ + dd) * TKP_;
#pragma unroll
        for (int m = 0; m < 2; ++m) {
            v4bf vv;
#pragma unroll
            for (int r = 0; r < 4; ++r) {
                int t = tbase + m * 16 + g * 4 + r;
                size_t row = (size_t)bbb * TKP_ + t;
                kcat[row * C_ + col] = (__bf16)(ak[m][n][r] + bkc);
                vv[r] = (__bf16)(av[m][n][r] + bvc);
            }
            // slot-permuted: t32 = m*16+g*4+r  ->  slot = g*8 + m*4 + r
            *(v4bf*)(vTr + vrow + tbase + g * 8 + m * 4) = vv;
        }
    }
}

// ---- pre3: qproj (blocks 0..575) || mempart (blocks 576..671) ----
__global__ __launch_bounds__(256) void k_pre3(const float* __restrict__ x,
        const float* __restrict__ lnw, const float* __restrict__ lnb,
        const __bf16* __restrict__ wqT, const float* __restrict__ bq,
        __bf16* __restrict__ q,
        const __bf16* __restrict__ kcat, const __bf16* __restrict__ vTr,
        float* __restrict__ kp, float* __restrict__ vp) {
    if (blockIdx.x >= 576) {
        int e = blockIdx.x - 576;              // 0..95
        int m = e / 12, ch = e % 12;
        int j = threadIdx.x;
        if (j < 192) {
            int hh = j >> 5, dd = j & 31;
            float sk = 0.f, sv = 0.f;
            for (int bb = 0; bb < 2; ++bb) {
                const __bf16* kpp = kcat + ((size_t)bb * TKP_ + m * 288 + ch * 24) * C_ + j;
                for (int t = 0; t < 24; ++t) sk += (float)kpp[t * C_];
                const __bf16* p = vTr + ((size_t)(bb * 6 + hh) * HD_ + dd) * TKP_ + m * 288 + ch * 24;
                for (int t = 0; t < 24; t += 8) {
                    v8bf v = *(const v8bf*)(p + t);
#pragma unroll
                    for (int u = 0; u < 8; ++u) sv += (float)v[u];
                }
            }
            kp[(m * 12 + ch) * C_ + j] = sk;
            vp[(m * 12 + ch) * C_ + j] = sv;
        }
        return;
    }
    __shared__ float  Of[32][196];
    __shared__ __bf16 Abf[32][200];
    __shared__ float  mu_s[32], rs_s[32];
    int tid = threadIdx.x;
    int w = tid >> 6, lane = tid & 63, qi = lane & 15, g = lane >> 4;
    size_t row0 = (size_t)blockIdx.x * 32;

    for (int e = tid; e < 32 * 48; e += 256) {
        int r = e / 48, c4 = e % 48;
        *(float4*)&Of[r][c4 * 4] = *(const float4*)(x + (row0 + r) * C_ + c4 * 4);
    }
    __syncthreads();
    {
        int r = tid >> 3, part8 = tid & 7;
        float s = 0.f, ss = 0.f;
        for (int i = 0; i < 24; ++i) { float a = Of[r][part8 * 24 + i]; s += a; ss += a * a; }
        s += __shfl_xor(s, 1); ss += __shfl_xor(ss, 1);
        s += __shfl_xor(s, 2); ss += __shfl_xor(ss, 2);
        s += __shfl_xor(s, 4); ss += __shfl_xor(ss, 4);
        if (part8 == 0) {
            float m = s * (1.f / C_);
            float var = ss * (1.f / C_) - m * m;
            mu_s[r] = m; rs_s[r] = rsqrtf(var + EPS_);
        }
    }
    __syncthreads();
    {
        int r = tid >> 3, part8 = tid & 7;
        float m = mu_s[r], rv = rs_s[r];
        for (int i = 0; i < 24; ++i) {
            int c = part8 * 24 + i;
            Abf[r][c] = (__bf16)((Of[r][c] - m) * rv * lnw[c] + lnb[c]);
        }
    }
    __syncthreads();

    v4f acc[2][3];
#pragma unroll
    for (int m = 0; m < 2; ++m)
#pragma unroll
        for (int n = 0; n < 3; ++n) acc[m][n] = (v4f){0.f, 0.f, 0.f, 0.f};
#pragma unroll
    for (int kk = 0; kk < 6; ++kk) {
        v8bf a0 = *(const v8bf*)&Abf[qi][kk * 32 + g * 8];
        v8bf a1 = *(const v8bf*)&Abf[16 + qi][kk * 32 + g * 8];
#pragma unroll
        for (int n = 0; n < 3; ++n) {
            v8bf bfr = *(const v8bf*)(wqT + (size_t)(w * 48 + n * 16 + qi) * C_ + kk * 32 + g * 8);
            acc[0][n] = MFMA16(a0, bfr, acc[0][n]);
            acc[1][n] = MFMA16(a1, bfr, acc[1][n]);
        }
    }
#pragma unroll
    for (int n = 0; n < 3; ++n) {
        int col = w * 48 + n * 16 + qi;
        float bb = bq[col];
#pragma unroll
        for (int m = 0; m < 2; ++m)
#pragma unroll
            for (int r = 0; r < 4; ++r)
                q[(row0 + m * 16 + g * 4 + r) * C_ + col] = (__bf16)((acc[m][n][r] + bb) * QSCALE_);
    }
}

// ------- EMA memory rows (blocks 0..7) + zero pad slots (blocks 8..31) -------
__global__ void k_memfin(const float* __restrict__ meanx,
                         const float* __restrict__ kp, const float* __restrict__ vp,
                         __bf16* __restrict__ kcat, __bf16* __restrict__ vTr) {
    int m = blockIdx.x, j = threadIdx.x;
    int hh = j >> 5, dd = j & 31;
    if (m < 8) {
        float sk = 0.f, sv = 0.f;
        for (int ch = 0; ch < 12; ++ch) {
            sk += kp[(m * 12 + ch) * C_ + j];
            sv += vp[(m * 12 + ch) * C_ + j];
        }
        float mk = 0.99f * meanx[j] + 0.01f * sk * (1.0f / 576.0f);
        float mv = sv * (0.01f / 576.0f);
        for (int bb = 0; bb < 2; ++bb)
            kcat[((size_t)bb * TKP_ + T_ + m) * C_ + j] = (__bf16)mk;
        int slot = (m >> 2) * 8 + (m & 3);     // t32 = m (<16)
        for (int bb = 0; bb < 2; ++bb)
            vTr[((size_t)(bb * 6 + hh) * HD_ + dd) * TKP_ + T_ + slot] = (__bf16)mv;
    } else {
        int t32 = m;                           // 8..31 within block at base T_
        int slot = (t32 < 16) ? ((t32 >> 2) * 8 + (t32 & 3))
                              : (((t32 >> 2) - 4) * 8 + 4 + (t32 & 3));
        for (int bb = 0; bb < 2; ++bb) {
            kcat[((size_t)bb * TKP_ + TK_ + (m - 8)) * C_ + j] = (__bf16)0.f;
            vTr[((size_t)(bb * 6 + hh) * HD_ + dd) * TKP_ + T_ + slot] = (__bf16)0.f;
        }
    }
}

// ------- MFMA attention: 1-wave blocks, 64 q/wave (4 tiles), 4-way key split -------
// S^T = mfma(K,Q); p = raw v_exp_f32(s); PV B-frag = own lane's p (V slot-permuted);
// ps as scalar f32 adds (end-of-loop shfl reduce). Natural VGPR allocation
// (no forced min-waves: round 13's (64,8) forcing caused a 4.7x spill disaster).
__global__ __launch_bounds__(64) void k_attn(const __bf16* __restrict__ q,
                                             const __bf16* __restrict__ kc,
                                             const __bf16* __restrict__ vt,
                                             __bf16* __restrict__ po,
                                             float* __restrict__ psb) {
    int lane = threadIdx.x & 63, g = lane >> 4, qi = lane & 15;
    int bs = blockIdx.z;                       // bb*4 + split
    int bb = bs >> 2, sp = bs & 3;
    int h = blockIdx.y;
    int qt = blockIdx.x * 64;
    int kv_lo = sp * 576;
    int kv_hi = (sp == 3) ? TKP_ : kv_lo + 576;
    const size_t BNC = (size_t)B_ * N_ * C_;

    v8bf qf[4];
#pragma unroll
    for (int t = 0; t < 4; ++t)
        qf[t] = *(const v8bf*)(q + ((size_t)bb * N_ + qt + t * 16 + qi) * C_ + h * HD_ + g * 8);

    v4f o0[4], o1[4];
    float ps[4];
#pragma unroll
    for (int t = 0; t < 4; ++t) {
        o0[t] = (v4f){0.f,0.f,0.f,0.f};
        o1[t] = (v4f){0.f,0.f,0.f,0.f};
        ps[t] = 0.f;
    }

    const __bf16* kbase = kc + ((size_t)bb * TKP_ + qi) * C_ + h * HD_ + g * 8;
    const __bf16* vb0 = vt + ((size_t)((bb * 6 + h) * HD_) + qi) * TKP_ + g * 8;
    const __bf16* vb1 = vb0 + (size_t)16 * TKP_;

    for (int kv0 = kv_lo; kv0 < kv_hi; kv0 += 32) {
        v8bf kf0 = *(const v8bf*)(kbase + (size_t)kv0 * C_);
        v8bf kf1 = *(const v8bf*)(kbase + (size_t)(kv0 + 16) * C_);
        v8bf va0 = *(const v8bf*)(vb0 + kv0);
        v8bf va1 = *(const v8bf*)(vb1 + kv0);
        v4f z = {0.f,0.f,0.f,0.f};
#pragma unroll
        for (int t = 0; t < 4; ++t) {
            v4f s0 = MFMA16(kf0, qf[t], z);
            v4f s1 = MFMA16(kf1, qf[t], z);
            v8bf pb;                            // slots j<4: keys g*4+j; j>=4: 16+g*4+j-4
#pragma unroll
            for (int r = 0; r < 4; ++r) {
                float e0 = __builtin_amdgcn_exp2f(s0[r]);
                float e1 = __builtin_amdgcn_exp2f(s1[r]);
                ps[t] += e0 + e1;
                pb[r]     = (__bf16)e0;
                pb[4 + r] = (__bf16)e1;
            }
            o0[t] = MFMA16(va0, pb, o0[t]);
            o1[t] = MFMA16(va1, pb, o1[t]);
        }
    }

    __bf16* pbase = po + (size_t)sp * BNC;
#pragma unroll
    for (int t = 0; t < 4; ++t) {
        ps[t] += __shfl_xor(ps[t], 16);
        ps[t] += __shfl_xor(ps[t], 32);
        __bf16* orow = pbase + ((size_t)bb * N_ + qt + t * 16 + qi) * C_ + h * HD_;
        v4bf a, b;
#pragma unroll
        for (int r = 0; r < 4; ++r) { a[r] = (__bf16)o0[t][r]; b[r] = (__bf16)o1[t][r]; }
        *(v4bf*)(orow + g * 4)      = a;
        *(v4bf*)(orow + 16 + g * 4) = b;
    }
    if (lane < 16) {                           // all g-lanes now hold full sums
#pragma unroll
        for (int t = 0; t < 4; ++t)
            psb[((size_t)bs * 6 + h) * N_ + qt + t * 16 + qi] = ps[t];
    }
}

// ---- MFMA post (merge fused): ao = Σpo/ps -> @wo+bo -> reg-LN -> MLP -> +res ----
__global__ __launch_bounds__(256) void k_post(const __bf16* __restrict__ po,
        const float* __restrict__ psb,
        const __bf16* __restrict__ woT, const float* __restrict__ bo,
        const float* __restrict__ ln2w, const float* __restrict__ ln2b,
        const __bf16* __restrict__ w1T, const float* __restrict__ b1,
        const __bf16* __restrict__ w2T, const float* __restrict__ b2,
        float* __restrict__ out) {
    __shared__ __bf16 Abf[32][200];
    __shared__ __bf16 H[32][392];
    __shared__ float  partLN[4][32][2];
    __shared__ float  mu_s[32], rs_s[32];
    __shared__ float  inv_s[32][6];
    int tid = threadIdx.x;
    int w = tid >> 6, lane = tid & 63, qi = lane & 15, g = lane >> 4;
    size_t row0 = (size_t)blockIdx.x * 32;
    const size_t BNC = (size_t)B_ * N_ * C_;

    // per-(row,head) denominators: sum of 4 split partials - pad correction
    if (tid < 192) {
        int r = tid / 6, h = tid % 6;
        size_t n = row0 + r;
        int bb = (n >= N_) ? 1 : 0;
        int nn = (int)(n - (size_t)bb * N_);
        float s = -(float)NPAD_;
#pragma unroll
        for (int sp = 0; sp < 4; ++sp)
            s += psb[((size_t)(bb * 4 + sp) * 6 + h) * N_ + nn];
        inv_s[r][h] = 1.f / s;
    }
    __syncthreads();

    // merge 4 bf16 partials -> normalized bf16 A tile
    for (int e = tid; e < 32 * 48; e += 256) {
        int r = e / 48, c4 = e % 48;
        float iv = inv_s[r][c4 >> 3];
        size_t n = row0 + r;
        float acc[4] = {0.f, 0.f, 0.f, 0.f};
#pragma unroll
        for (int sp = 0; sp < 4; ++sp) {
            v4bf v = *(const v4bf*)(po + (size_t)sp * BNC + n * C_ + c4 * 4);
#pragma unroll
            for (int u = 0; u < 4; ++u) acc[u] += (float)v[u];
        }
        v4bf pbf;
#pragma unroll
        for (int u = 0; u < 4; ++u) pbf[u] = (__bf16)(acc[u] * iv);
        *(v4bf*)&Abf[r][c4 * 4] = pbf;
    }
    __syncthreads();

    // GEMM1: o = A @ wo + bo (kept in regs for residual + LN)
    v4f acc1[2][3];
#pragma unroll
    for (int m = 0; m < 2; ++m)
#pragma unroll
        for (int n = 0; n < 3; ++n) acc1[m][n] = (v4f){0.f,0.f,0.f,0.f};
#pragma unroll
    for (int kk = 0; kk < 6; ++kk) {
        v8bf a0 = *(const v8bf*)&Abf[qi][kk * 32 + g * 8];
        v8bf a1 = *(const v8bf*)&Abf[16 + qi][kk * 32 + g * 8];
#pragma unroll
        for (int n = 0; n < 3; ++n) {
            v8bf bfr = *(const v8bf*)(woT + (size_t)(w * 48 + n * 16 + qi) * C_ + kk * 32 + g * 8);
            acc1[0][n] = MFMA16(a0, bfr, acc1[0][n]);
            acc1[1][n] = MFMA16(a1, bfr, acc1[1][n]);
        }
    }
#pragma unroll
    for (int n = 0; n < 3; ++n) {
        float bb = bo[w * 48 + n * 16 + qi];
#pragma unroll
        for (int m = 0; m < 2; ++m)
#pragma unroll
            for (int r = 0; r < 4; ++r) acc1[m][n][r] += bb;
    }

    // register LN: per-row stats via qi-shuffles + 1KB cross-wave partials
    {
        float sr[2][4], qr[2][4];
#pragma unroll
        for (int m = 0; m < 2; ++m)
#pragma unroll
            for (int r = 0; r < 4; ++r) {
                float s = acc1[m][0][r] + acc1[m][1][r] + acc1[m][2][r];
                float q2 = acc1[m][0][r] * acc1[m][0][r] + acc1[m][1][r] * acc1[m][1][r]
                         + acc1[m][2][r] * acc1[m][2][r];
                s += __shfl_xor(s, 1); q2 += __shfl_xor(q2, 1);
                s += __shfl_xor(s, 2); q2 += __shfl_xor(q2, 2);
                s += __shfl_xor(s, 4); q2 += __shfl_xor(q2, 4);
                s += __shfl_xor(s, 8); q2 += __shfl_xor(q2, 8);
                sr[m][r] = s; qr[m][r] = q2;
            }
        if (qi == 0) {
#pragma unroll
            for (int m = 0; m < 2; ++m)
#pragma unroll
                for (int r = 0; r < 4; ++r) {
                    partLN[w][m * 16 + g * 4 + r][0] = sr[m][r];
                    partLN[w][m * 16 + g * 4 + r][1] = qr[m][r];
                }
        }
    }
    __syncthreads();
    if (tid < 32) {
        float s  = partLN[0][tid][0] + partLN[1][tid][0] + partLN[2][tid][0] + partLN[3][tid][0];
        float q2 = partLN[0][tid][1] + partLN[1][tid][1] + partLN[2][tid][1] + partLN[3][tid][1];
        float mm = s * (1.f / C_);
        float var = q2 * (1.f / C_) - mm * mm;
        mu_s[tid] = mm; rs_s[tid] = rsqrtf(var + EPS_);
    }
    __syncthreads();
    // write LN'd values to Abf straight from registers
#pragma unroll
    for (int n = 0; n < 3; ++n) {
        int col = w * 48 + n * 16 + qi;
        float lw = ln2w[col], lb = ln2b[col];
#pragma unroll
        for (int m = 0; m < 2; ++m)
#pragma unroll
            for (int r = 0; r < 4; ++r) {
                int row = m * 16 + g * 4 + r;
                Abf[row][col] = (__bf16)((acc1[m][n][r] - mu_s[row]) * rs_s[row] * lw + lb);
            }
    }
    __syncthreads();

    // GEMM2: g = h @ w1 + b1, GELU -> H
    v4f acc2[2][6];
#pragma unroll
    for (int m = 0; m < 2; ++m)
#pragma unroll
        for (int n = 0; n < 6; ++n) acc2[m][n] = (v4f){0.f,0.f,0.f,0.f};
#pragma unroll
    for (int kk = 0; kk < 6; ++kk) {
        v8bf a0 = *(const v8bf*)&Abf[qi][kk * 32 + g * 8];
        v8bf a1 = *(const v8bf*)&Abf[16 + qi][kk * 32 + g * 8];
#pragma unroll
        for (int n = 0; n < 6; ++n) {
            v8bf bfr = *(const v8bf*)(w1T + (size_t)(w * 96 + n * 16 + qi) * C_ + kk * 32 + g * 8);
            acc2[0][n] = MFMA16(a0, bfr, acc2[0][n]);
            acc2[1][n] = MFMA16(a1, bfr, acc2[1][n]);
        }
    }
#pragma unroll
    for (int n = 0; n < 6; ++n) {
        int col = w * 96 + n * 16 + qi;
        float bb = b1[col];
#pragma unroll
        for (int m = 0; m < 2; ++m)
#pragma unroll
            for (int r = 0; r < 4; ++r)
                H[m * 16 + g * 4 + r][col] = (__bf16)gelu_erf(acc2[m][n][r] + bb);
    }
    __syncthreads();

    // GEMM3: f = g @ w2 + b2; out = o + f
    v4f acc3[2][3];
#pragma unroll
    for (int m = 0; m < 2; ++m)
#pragma unroll
        for (int n = 0; n < 3; ++n) acc3[m][n] = (v4f){0.f,0.f,0.f,0.f};
#pragma unroll
    for (int kk = 0; kk < 12; ++kk) {
        v8bf a0 = *(const v8bf*)&H[qi][kk * 32 + g * 8];
        v8bf a1 = *(const v8bf*)&H[16 + qi][kk * 32 + g * 8];
#pragma unroll
        for (int n = 0; n < 3; ++n) {
            v8bf bfr = *(const v8bf*)(w2T + (size_t)(w * 48 + n * 16 + qi) * MLPH_ + kk * 32 + g * 8);
            acc3[0][n] = MFMA16(a0, bfr, acc3[0][n]);
            acc3[1][n] = MFMA16(a1, bfr, acc3[1][n]);
        }
    }
#pragma unroll
    for (int n = 0; n < 3; ++n) {
        int col = w * 48 + n * 16 + qi;
        float bb = b2[col];
#pragma unroll
        for (int m = 0; m < 2; ++m)
#pragma unroll
            for (int r = 0; r < 4; ++r)
                out[(row0 + m * 16 + g * 4 + r) * C_ + col] = acc1[m][n][r] + acc3[m][n][r] + bb;
    }
}

extern "C" void kernel_launch(void* const* d_in, const int* in_sizes, int n_in,
                              void* d_out, int out_size, void* d_ws, size_t ws_size,
                              hipStream_t stream) {
    const float* x    = (const float*)d_in[0];
    const float* lnqw = (const float*)d_in[1];
    const float* lnqb = (const float*)d_in[2];
    const float* lnkw = (const float*)d_in[3];
    const float* lnkb = (const float*)d_in[4];
    const float* wq   = (const float*)d_in[5];
    const float* bq   = (const float*)d_in[6];
    const float* wk   = (const float*)d_in[7];
    const float* bk   = (const float*)d_in[8];
    const float* wv   = (const float*)d_in[9];
    const float* bv   = (const float*)d_in[10];
    const float* wo   = (const float*)d_in[11];
    const float* bo   = (const float*)d_in[12];
    const float* ln2w = (const float*)d_in[13];
    const float* ln2b = (const float*)d_in[14];
    const float* w1   = (const float*)d_in[15];
    const float* b1   = (const float*)d_in[16];
    const float* w2   = (const float*)d_in[17];
    const float* b2   = (const float*)d_in[18];

    char* w0 = (char*)d_ws;
    const size_t QB  = (size_t)B_ * N_ * C_ * 2;       // 7,077,888
    const size_t KVB = (size_t)B_ * TKP_ * C_ * 2;     // 1,794,048
    const size_t POB = (size_t)4 * B_ * N_ * C_ * 2;   // 28,311,552 (4 bf16 splits)
    __bf16* qb  = (__bf16*)(w0);
    __bf16* kcb = (__bf16*)(w0 + QB);
    __bf16* vtr = (__bf16*)(w0 + QB + KVB);
    __bf16* po  = (__bf16*)(w0 + QB + 2 * KVB);
    float*  psb = (float*) (w0 + QB + 2 * KVB + POB);    // 8*6*N f32
    float*  kp    = psb + (size_t)8 * 6 * N_;            // 96*192
    float*  vp    = kp + 96 * C_;                        // 96*192
    float*  part  = vp + 96 * C_;                        // 144*192
    float*  meanx = part + 144 * C_;
    char* wbase = (char*)(meanx + 192 + 32);
    wbase = (char*)(((uintptr_t)wbase + 255) & ~(uintptr_t)255);
    __bf16* wqT = (__bf16*)(wbase);
    __bf16* wkT = wqT + 36864;
    __bf16* wvT = wkT + 36864;
    __bf16* woT = wvT + 36864;
    __bf16* w1T = woT + 36864;
    __bf16* w2T = w1T + 73728;

    hipLaunchKernelGGL(k_pre1, dim3(432), dim3(256), 0, stream,
                       wq, wk, wv, wo, w1, w2, wqT, wkT, wvT, woT, w1T, w2T, x, part);
    hipLaunchKernelGGL(k_pre2, dim3(145), dim3(256), 0, stream,
                       x, lnkw, lnkb, wkT, bk, wvT, bv, kcb, vtr, part, meanx);
    hipLaunchKernelGGL(k_pre3, dim3(672), dim3(256), 0, stream,
                       x, lnqw, lnqb, wqT, bq, qb, kcb, vtr, kp, vp);
    hipLaunchKernelGGL(k_memfin, dim3(32), dim3(192), 0, stream, meanx, kp, vp, kcb, vtr);
    hipLaunchKernelGGL(k_attn, dim3(144, 6, 8), dim3(64), 0, stream,
                       qb, kcb, vtr, po, psb);
    hipLaunchKernelGGL(k_post, dim3(576), dim3(256), 0, stream,
                       po, psb, woT, bo, ln2w, ln2b, w1T, b1, w2T, b2, (float*)d_out);
}

// Round 15
// 138.673 us; speedup vs baseline: 2.8547x; 1.0189x over previous
//
#include <hip/hip_runtime.h>
#include <hip/hip_bf16.h>
#include <math.h>

#define B_    2
#define N_    9216
#define C_    192
#define HD_   32
#define T_    2304
#define MEM_  8
#define TK_   2312      // T_ + MEM_
#define TKP_  2336      // padded to multiple of 32
#define NPAD_ 24        // TKP_ - TK_
#define MLPH_ 384
#define SCALE_ 0.17677669529663687f
// SCALE * log2(e): q is pre-scaled so attn can use exp2 directly
#define QSCALE_ 0.25504167229218905f
#define EPS_  1e-5f

typedef __bf16 v8bf __attribute__((ext_vector_type(8)));
typedef __bf16 v4bf __attribute__((ext_vector_type(4)));
typedef float  v4f  __attribute__((ext_vector_type(4)));

#define MFMA16(a, b, c) __builtin_amdgcn_mfma_f32_16x16x32_bf16((a), (b), (c), 0, 0, 0)

static __device__ __forceinline__ float gelu_erf(float x) {
    return 0.5f * x * (1.0f + erff(x * 0.70710678118654752f));
}

// ---- pre1: weight transpose (blocks 0..287) || x row-partials (blocks 288..431) ----
__global__ __launch_bounds__(256) void k_pre1(const float* __restrict__ wq,
                       const float* __restrict__ wk,
                       const float* __restrict__ wv, const float* __restrict__ wo,
                       const float* __restrict__ w1, const float* __restrict__ w2,
                       __bf16* __restrict__ wqT, __bf16* __restrict__ wkT,
                       __bf16* __restrict__ wvT, __bf16* __restrict__ woT,
                       __bf16* __restrict__ w1T, __bf16* __restrict__ w2T,
                       const float* __restrict__ x, float* __restrict__ part) {
    __shared__ float tile[32][33];
    int b = blockIdx.x;
    if (b < 288) {
        const float* src; __bf16* dst; int K, Nn, t0;
        if (b < 144)      { int m = b / 36; t0 = b % 36;
                            src = m==0?wq:m==1?wk:m==2?wv:wo;
                            dst = m==0?wqT:m==1?wkT:m==2?wvT:woT; K=192; Nn=192; }
        else if (b < 216) { t0 = b - 144; src = w1; dst = w1T; K=192; Nn=384; }
        else              { t0 = b - 216; src = w2; dst = w2T; K=384; Nn=192; }
        int ntn = Nn / 32;
        int k0 = (t0 / ntn) * 32, n0 = (t0 % ntn) * 32;
        int r = threadIdx.x >> 5, c = threadIdx.x & 31;
#pragma unroll
        for (int i = 0; i < 4; ++i)
            tile[r + i * 8][c] = src[(size_t)(k0 + r + i * 8) * Nn + n0 + c];
        __syncthreads();
#pragma unroll
        for (int i = 0; i < 4; ++i)
            dst[(size_t)(n0 + r + i * 8) * K + k0 + c] = (__bf16)tile[c][r + i * 8];
    } else {
        int j = threadIdx.x;
        if (j < 192) {
            const float* p = x + (size_t)(b - 288) * 128 * C_;
            float s = 0.f;
            for (int r = 0; r < 128; ++r) s += p[r * C_ + j];
            part[(b - 288) * C_ + j] = s;
        }
    }
}

// ------- pre2: kvproj (blocks 0..143) || meanfin (block 144) -------
__global__ __launch_bounds__(256) void k_pre2(const float* __restrict__ x,
        const float* __restrict__ lnw, const float* __restrict__ lnb,
        const __bf16* __restrict__ wkT, const float* __restrict__ bk,
        const __bf16* __restrict__ wvT, const float* __restrict__ bv,
        __bf16* __restrict__ kcat, __bf16* __restrict__ vTr,
        const float* __restrict__ part, float* __restrict__ meanx) {
    if (blockIdx.x == 144) {
        int j = threadIdx.x;
        if (j < 192) {
            float s = 0.f;
            for (int i = 0; i < 144; ++i) s += part[i * C_ + j];
            meanx[j] = s * (1.0f / 18432.0f);
        }
        return;
    }
    __shared__ float  Of[32][196];
    __shared__ __bf16 Abf[32][200];
    __shared__ float  mu_s[32], rs_s[32];
    int tid = threadIdx.x;
    int w = tid >> 6, lane = tid & 63, qi = lane & 15, g = lane >> 4;
    int p0 = blockIdx.x * 32;
    int bbb = p0 / T_, tbase = p0 % T_;

    for (int e = tid; e < 32 * 48; e += 256) {
        int r = e / 48, c4 = e % 48;
        int t = tbase + r;
        int h2 = t / 48, w2c = t % 48;
        const float* s0 = x + ((size_t)bbb * N_ + (size_t)(2 * h2) * 96 + 2 * w2c) * C_ + c4 * 4;
        float4 u0 = *(const float4*)(s0);
        float4 u1 = *(const float4*)(s0 + C_);
        float4 u2 = *(const float4*)(s0 + 96 * C_);
        float4 u3 = *(const float4*)(s0 + 96 * C_ + C_);
        float4 a;
        a.x = 0.25f * (u0.x + u1.x + u2.x + u3.x);
        a.y = 0.25f * (u0.y + u1.y + u2.y + u3.y);
        a.z = 0.25f * (u0.z + u1.z + u2.z + u3.z);
        a.w = 0.25f * (u0.w + u1.w + u2.w + u3.w);
        *(float4*)&Of[r][c4 * 4] = a;
    }
    __syncthreads();
    {
        int r = tid >> 3, part8 = tid & 7;
        float s = 0.f, ss = 0.f;
        for (int i = 0; i < 24; ++i) { float a = Of[r][part8 * 24 + i]; s += a; ss += a * a; }
        s += __shfl_xor(s, 1); ss += __shfl_xor(ss, 1);
        s += __shfl_xor(s, 2); ss += __shfl_xor(ss, 2);
        s += __shfl_xor(s, 4); ss += __shfl_xor(ss, 4);
        if (part8 == 0) {
            float m = s * (1.f / C_);
            float var = ss * (1.f / C_) - m * m;
            mu_s[r] = m; rs_s[r] = rsqrtf(var + EPS_);
        }
    }
    __syncthreads();
    {
        int r = tid >> 3, part8 = tid & 7;
        float m = mu_s[r], rv = rs_s[r];
        for (int i = 0; i < 24; ++i) {
            int c = part8 * 24 + i;
            Abf[r][c] = (__bf16)((Of[r][c] - m) * rv * lnw[c] + lnb[c]);
        }
    }
    __syncthreads();

    v4f ak[2][3], av[2][3];
#pragma unroll
    for (int m = 0; m < 2; ++m)
#pragma unroll
        for (int n = 0; n < 3; ++n) { ak[m][n] = (v4f){0.f,0.f,0.f,0.f}; av[m][n] = (v4f){0.f,0.f,0.f,0.f}; }
#pragma unroll
    for (int kk = 0; kk < 6; ++kk) {
        v8bf a0 = *(const v8bf*)&Abf[qi][kk * 32 + g * 8];
        v8bf a1 = *(const v8bf*)&Abf[16 + qi][kk * 32 + g * 8];
#pragma unroll
        for (int n = 0; n < 3; ++n) {
            int col = w * 48 + n * 16 + qi;
            v8bf bk8 = *(const v8bf*)(wkT + (size_t)col * C_ + kk * 32 + g * 8);
            v8bf bv8 = *(const v8bf*)(wvT + (size_t)col * C_ + kk * 32 + g * 8);
            ak[0][n] = MFMA16(a0, bk8, ak[0][n]);
            ak[1][n] = MFMA16(a1, bk8, ak[1][n]);
            av[0][n] = MFMA16(a0, bv8, av[0][n]);
            av[1][n] = MFMA16(a1, bv8, av[1][n]);
        }
    }
#pragma unroll
    for (int n = 0; n < 3; ++n) {
        int col = w * 48 + n * 16 + qi;
        float bkc = bk[col], bvc = bv[col];
        int hh = col >> 5, dd = col & 31;
        size_t vrow = ((size_t)(bbb * 6 + hh) * HD_ + dd) * TKP_;
#pragma unroll
        for (int m = 0; m < 2; ++m) {
            v4bf vv;
#pragma unroll
            for (int r = 0; r < 4; ++r) {
                int t = tbase + m * 16 + g * 4 + r;
                size_t row = (size_t)bbb * TKP_ + t;
                kcat[row * C_ + col] = (__bf16)(ak[m][n][r] + bkc);
                vv[r] = (__bf16)(av[m][n][r] + bvc);
            }
            // slot-permuted: t32 = m*16+g*4+r  ->  slot = g*8 + m*4 + r
            *(v4bf*)(vTr + vrow + tbase + g * 8 + m * 4) = vv;
        }
    }
}

// ---- pre3: qproj (blocks 0..575) || mempart (blocks 576..671) ----
__global__ __launch_bounds__(256) void k_pre3(const float* __restrict__ x,
        const float* __restrict__ lnw, const float* __restrict__ lnb,
        const __bf16* __restrict__ wqT, const float* __restrict__ bq,
        __bf16* __restrict__ q,
        const __bf16* __restrict__ kcat, const __bf16* __restrict__ vTr,
        float* __restrict__ kp, float* __restrict__ vp) {
    if (blockIdx.x >= 576) {
        int e = blockIdx.x - 576;              // 0..95
        int m = e / 12, ch = e % 12;
        int j = threadIdx.x;
        if (j < 192) {
            int hh = j >> 5, dd = j & 31;
            float sk = 0.f, sv = 0.f;
            for (int bb = 0; bb < 2; ++bb) {
                const __bf16* kpp = kcat + ((size_t)bb * TKP_ + m * 288 + ch * 24) * C_ + j;
                for (int t = 0; t < 24; ++t) sk += (float)kpp[t * C_];
                const __bf16* p = vTr + ((size_t)(bb * 6 + hh) * HD_ + dd) * TKP_ + m * 288 + ch * 24;
                for (int t = 0; t < 24; t += 8) {
                    v8bf v = *(const v8bf*)(p + t);
#pragma unroll
                    for (int u = 0; u < 8; ++u) sv += (float)v[u];
                }
            }
            kp[(m * 12 + ch) * C_ + j] = sk;
            vp[(m * 12 + ch) * C_ + j] = sv;
        }
        return;
    }
    __shared__ float  Of[32][196];
    __shared__ __bf16 Abf[32][200];
    __shared__ float  mu_s[32], rs_s[32];
    int tid = threadIdx.x;
    int w = tid >> 6, lane = tid & 63, qi = lane & 15, g = lane >> 4;
    size_t row0 = (size_t)blockIdx.x * 32;

    for (int e = tid; e < 32 * 48; e += 256) {
        int r = e / 48, c4 = e % 48;
        *(float4*)&Of[r][c4 * 4] = *(const float4*)(x + (row0 + r) * C_ + c4 * 4);
    }
    __syncthreads();
    {
        int r = tid >> 3, part8 = tid & 7;
        float s = 0.f, ss = 0.f;
        for (int i = 0; i < 24; ++i) { float a = Of[r][part8 * 24 + i]; s += a; ss += a * a; }
        s += __shfl_xor(s, 1); ss += __shfl_xor(ss, 1);
        s += __shfl_xor(s, 2); ss += __shfl_xor(ss, 2);
        s += __shfl_xor(s, 4); ss += __shfl_xor(ss, 4);
        if (part8 == 0) {
            float m = s * (1.f / C_);
            float var = ss * (1.f / C_) - m * m;
            mu_s[r] = m; rs_s[r] = rsqrtf(var + EPS_);
        }
    }
    __syncthreads();
    {
        int r = tid >> 3, part8 = tid & 7;
        float m = mu_s[r], rv = rs_s[r];
        for (int i = 0; i < 24; ++i) {
            int c = part8 * 24 + i;
            Abf[r][c] = (__bf16)((Of[r][c] - m) * rv * lnw[c] + lnb[c]);
        }
    }
    __syncthreads();

    v4f acc[2][3];
#pragma unroll
    for (int m = 0; m < 2; ++m)
#pragma unroll
        for (int n = 0; n < 3; ++n) acc[m][n] = (v4f){0.f, 0.f, 0.f, 0.f};
#pragma unroll
    for (int kk = 0; kk < 6; ++kk) {
        v8bf a0 = *(const v8bf*)&Abf[qi][kk * 32 + g * 8];
        v8bf a1 = *(const v8bf*)&Abf[16 + qi][kk * 32 + g * 8];
#pragma unroll
        for (int n = 0; n < 3; ++n) {
            v8bf bfr = *(const v8bf*)(wqT + (size_t)(w * 48 + n * 16 + qi) * C_ + kk * 32 + g * 8);
            acc[0][n] = MFMA16(a0, bfr, acc[0][n]);
            acc[1][n] = MFMA16(a1, bfr, acc[1][n]);
        }
    }
#pragma unroll
    for (int n = 0; n < 3; ++n) {
        int col = w * 48 + n * 16 + qi;
        float bb = bq[col];
#pragma unroll
        for (int m = 0; m < 2; ++m)
#pragma unroll
            for (int r = 0; r < 4; ++r)
                q[(row0 + m * 16 + g * 4 + r) * C_ + col] = (__bf16)((acc[m][n][r] + bb) * QSCALE_);
    }
}

// ------- EMA memory rows (blocks 0..7) + zero pad slots (blocks 8..31) -------
__global__ void k_memfin(const float* __restrict__ meanx,
                         const float* __restrict__ kp, const float* __restrict__ vp,
                         __bf16* __restrict__ kcat, __bf16* __restrict__ vTr) {
    int m = blockIdx.x, j = threadIdx.x;
    int hh = j >> 5, dd = j & 31;
    if (m < 8) {
        float sk = 0.f, sv = 0.f;
        for (int ch = 0; ch < 12; ++ch) {
            sk += kp[(m * 12 + ch) * C_ + j];
            sv += vp[(m * 12 + ch) * C_ + j];
        }
        float mk = 0.99f * meanx[j] + 0.01f * sk * (1.0f / 576.0f);
        float mv = sv * (0.01f / 576.0f);
        for (int bb = 0; bb < 2; ++bb)
            kcat[((size_t)bb * TKP_ + T_ + m) * C_ + j] = (__bf16)mk;
        int slot = (m >> 2) * 8 + (m & 3);     // t32 = m (<16)
        for (int bb = 0; bb < 2; ++bb)
            vTr[((size_t)(bb * 6 + hh) * HD_ + dd) * TKP_ + T_ + slot] = (__bf16)mv;
    } else {
        int t32 = m;                           // 8..31 within block at base T_
        int slot = (t32 < 16) ? ((t32 >> 2) * 8 + (t32 & 3))
                              : (((t32 >> 2) - 4) * 8 + 4 + (t32 & 3));
        for (int bb = 0; bb < 2; ++bb) {
            kcat[((size_t)bb * TKP_ + TK_ + (m - 8)) * C_ + j] = (__bf16)0.f;
            vTr[((size_t)(bb * 6 + hh) * HD_ + dd) * TKP_ + T_ + slot] = (__bf16)0.f;
        }
    }
}

// ------- MFMA attention: 1-wave blocks, 64 q/wave (4 tiles), 4-way key split -------
// Next-tile K/V prefetch pinned ABOVE the compute via sched_barrier(0) (rule 18:
// without the barrier the compiler sinks the loads back to their uses — round 12).
// Waitcnt for prefetched regs then lands at next iter's first MFMA (~700 cyc later).
__global__ __launch_bounds__(64) void k_attn(const __bf16* __restrict__ q,
                                             const __bf16* __restrict__ kc,
                                             const __bf16* __restrict__ vt,
                                             __bf16* __restrict__ po,
                                             float* __restrict__ psb) {
    int lane = threadIdx.x & 63, g = lane >> 4, qi = lane & 15;
    int bs = blockIdx.z;                       // bb*4 + split
    int bb = bs >> 2, sp = bs & 3;
    int h = blockIdx.y;
    int qt = blockIdx.x * 64;
    int kv_lo = sp * 576;
    int kv_hi = (sp == 3) ? TKP_ : kv_lo + 576;
    const size_t BNC = (size_t)B_ * N_ * C_;

    v8bf qf[4];
#pragma unroll
    for (int t = 0; t < 4; ++t)
        qf[t] = *(const v8bf*)(q + ((size_t)bb * N_ + qt + t * 16 + qi) * C_ + h * HD_ + g * 8);

    v4f o0[4], o1[4];
    float ps[4];
#pragma unroll
    for (int t = 0; t < 4; ++t) {
        o0[t] = (v4f){0.f,0.f,0.f,0.f};
        o1[t] = (v4f){0.f,0.f,0.f,0.f};
        ps[t] = 0.f;
    }

    const __bf16* kbase = kc + ((size_t)bb * TKP_ + qi) * C_ + h * HD_ + g * 8;
    const __bf16* vb0 = vt + ((size_t)((bb * 6 + h) * HD_) + qi) * TKP_ + g * 8;
    const __bf16* vb1 = vb0 + (size_t)16 * TKP_;

    // prologue: first tile
    v8bf kf0 = *(const v8bf*)(kbase + (size_t)kv_lo * C_);
    v8bf kf1 = *(const v8bf*)(kbase + (size_t)(kv_lo + 16) * C_);
    v8bf va0 = *(const v8bf*)(vb0 + kv_lo);
    v8bf va1 = *(const v8bf*)(vb1 + kv_lo);

    for (int kv0 = kv_lo; kv0 < kv_hi; kv0 += 32) {
        // prefetch next tile; barrier pins the loads above the compute
        int nxt = (kv0 + 32 < kv_hi) ? (kv0 + 32) : kv_lo;
        v8bf nkf0 = *(const v8bf*)(kbase + (size_t)nxt * C_);
        v8bf nkf1 = *(const v8bf*)(kbase + (size_t)(nxt + 16) * C_);
        v8bf nva0 = *(const v8bf*)(vb0 + nxt);
        v8bf nva1 = *(const v8bf*)(vb1 + nxt);
        __builtin_amdgcn_sched_barrier(0);

        v4f z = {0.f,0.f,0.f,0.f};
#pragma unroll
        for (int t = 0; t < 4; ++t) {
            v4f s0 = MFMA16(kf0, qf[t], z);
            v4f s1 = MFMA16(kf1, qf[t], z);
            v8bf pb;                            // slots j<4: keys g*4+j; j>=4: 16+g*4+j-4
#pragma unroll
            for (int r = 0; r < 4; ++r) {
                float e0 = __builtin_amdgcn_exp2f(s0[r]);
                float e1 = __builtin_amdgcn_exp2f(s1[r]);
                ps[t] += e0 + e1;
                pb[r]     = (__bf16)e0;
                pb[4 + r] = (__bf16)e1;
            }
            o0[t] = MFMA16(va0, pb, o0[t]);
            o1[t] = MFMA16(va1, pb, o1[t]);
        }
        kf0 = nkf0; kf1 = nkf1; va0 = nva0; va1 = nva1;
    }

    __bf16* pbase = po + (size_t)sp * BNC;
#pragma unroll
    for (int t = 0; t < 4; ++t) {
        ps[t] += __shfl_xor(ps[t], 16);
        ps[t] += __shfl_xor(ps[t], 32);
        __bf16* orow = pbase + ((size_t)bb * N_ + qt + t * 16 + qi) * C_ + h * HD_;
        v4bf a, b;
#pragma unroll
        for (int r = 0; r < 4; ++r) { a[r] = (__bf16)o0[t][r]; b[r] = (__bf16)o1[t][r]; }
        *(v4bf*)(orow + g * 4)      = a;
        *(v4bf*)(orow + 16 + g * 4) = b;
    }
    if (lane < 16) {                           // all g-lanes hold full sums
#pragma unroll
        for (int t = 0; t < 4; ++t)
            psb[((size_t)bs * 6 + h) * N_ + qt + t * 16 + qi] = ps[t];
    }
}

// ---- MFMA post (merge fused): ao = Σpo/ps -> @wo+bo -> reg-LN -> MLP -> +res ----
__global__ __launch_bounds__(256) void k_post(const __bf16* __restrict__ po,
        const float* __restrict__ psb,
        const __bf16* __restrict__ woT, const float* __restrict__ bo,
        const float* __restrict__ ln2w, const float* __restrict__ ln2b,
        const __bf16* __restrict__ w1T, const float* __restrict__ b1,
        const __bf16* __restrict__ w2T, const float* __restrict__ b2,
        float* __restrict__ out) {
    __shared__ __bf16 Abf[32][200];
    __shared__ __bf16 H[32][392];
    __shared__ float  partLN[4][32][2];
    __shared__ float  mu_s[32], rs_s[32];
    __shared__ float  inv_s[32][6];
    int tid = threadIdx.x;
    int w = tid >> 6, lane = tid & 63, qi = lane & 15, g = lane >> 4;
    size_t row0 = (size_t)blockIdx.x * 32;
    const size_t BNC = (size_t)B_ * N_ * C_;

    // per-(row,head) denominators: sum of 4 split partials - pad correction
    if (tid < 192) {
        int r = tid / 6, h = tid % 6;
        size_t n = row0 + r;
        int bb = (n >= N_) ? 1 : 0;
        int nn = (int)(n - (size_t)bb * N_);
        float s = -(float)NPAD_;
#pragma unroll
        for (int sp = 0; sp < 4; ++sp)
            s += psb[((size_t)(bb * 4 + sp) * 6 + h) * N_ + nn];
        inv_s[r][h] = 1.f / s;
    }
    __syncthreads();

    // merge 4 bf16 partials -> normalized bf16 A tile
    for (int e = tid; e < 32 * 48; e += 256) {
        int r = e / 48, c4 = e % 48;
        float iv = inv_s[r][c4 >> 3];
        size_t n = row0 + r;
        float acc[4] = {0.f, 0.f, 0.f, 0.f};
#pragma unroll
        for (int sp = 0; sp < 4; ++sp) {
            v4bf v = *(const v4bf*)(po + (size_t)sp * BNC + n * C_ + c4 * 4);
#pragma unroll
            for (int u = 0; u < 4; ++u) acc[u] += (float)v[u];
        }
        v4bf pbf;
#pragma unroll
        for (int u = 0; u < 4; ++u) pbf[u] = (__bf16)(acc[u] * iv);
        *(v4bf*)&Abf[r][c4 * 4] = pbf;
    }
    __syncthreads();

    // GEMM1: o = A @ wo + bo (kept in regs for residual + LN)
    v4f acc1[2][3];
#pragma unroll
    for (int m = 0; m < 2; ++m)
#pragma unroll
        for (int n = 0; n < 3; ++n) acc1[m][n] = (v4f){0.f,0.f,0.f,0.f};
#pragma unroll
    for (int kk = 0; kk < 6; ++kk) {
        v8bf a0 = *(const v8bf*)&Abf[qi][kk * 32 + g * 8];
        v8bf a1 = *(const v8bf*)&Abf[16 + qi][kk * 32 + g * 8];
#pragma unroll
        for (int n = 0; n < 3; ++n) {
            v8bf bfr = *(const v8bf*)(woT + (size_t)(w * 48 + n * 16 + qi) * C_ + kk * 32 + g * 8);
            acc1[0][n] = MFMA16(a0, bfr, acc1[0][n]);
            acc1[1][n] = MFMA16(a1, bfr, acc1[1][n]);
        }
    }
#pragma unroll
    for (int n = 0; n < 3; ++n) {
        float bb = bo[w * 48 + n * 16 + qi];
#pragma unroll
        for (int m = 0; m < 2; ++m)
#pragma unroll
            for (int r = 0; r < 4; ++r) acc1[m][n][r] += bb;
    }

    // register LN: per-row stats via qi-shuffles + 1KB cross-wave partials
    {
        float sr[2][4], qr[2][4];
#pragma unroll
        for (int m = 0; m < 2; ++m)
#pragma unroll
            for (int r = 0; r < 4; ++r) {
                float s = acc1[m][0][r] + acc1[m][1][r] + acc1[m][2][r];
                float q2 = acc1[m][0][r] * acc1[m][0][r] + acc1[m][1][r] * acc1[m][1][r]
                         + acc1[m][2][r] * acc1[m][2][r];
                s += __shfl_xor(s, 1); q2 += __shfl_xor(q2, 1);
                s += __shfl_xor(s, 2); q2 += __shfl_xor(q2, 2);
                s += __shfl_xor(s, 4); q2 += __shfl_xor(q2, 4);
                s += __shfl_xor(s, 8); q2 += __shfl_xor(q2, 8);
                sr[m][r] = s; qr[m][r] = q2;
            }
        if (qi == 0) {
#pragma unroll
            for (int m = 0; m < 2; ++m)
#pragma unroll
                for (int r = 0; r < 4; ++r) {
                    partLN[w][m * 16 + g * 4 + r][0] = sr[m][r];
                    partLN[w][m * 16 + g * 4 + r][1] = qr[m][r];
                }
        }
    }
    __syncthreads();
    if (tid < 32) {
        float s  = partLN[0][tid][0] + partLN[1][tid][0] + partLN[2][tid][0] + partLN[3][tid][0];
        float q2 = partLN[0][tid][1] + partLN[1][tid][1] + partLN[2][tid][1] + partLN[3][tid][1];
        float mm = s * (1.f / C_);
        float var = q2 * (1.f / C_) - mm * mm;
        mu_s[tid] = mm; rs_s[tid] = rsqrtf(var + EPS_);
    }
    __syncthreads();
    // write LN'd values to Abf straight from registers
#pragma unroll
    for (int n = 0; n < 3; ++n) {
        int col = w * 48 + n * 16 + qi;
        float lw = ln2w[col], lb = ln2b[col];
#pragma unroll
        for (int m = 0; m < 2; ++m)
#pragma unroll
            for (int r = 0; r < 4; ++r) {
                int row = m * 16 + g * 4 + r;
                Abf[row][col] = (__bf16)((acc1[m][n][r] - mu_s[row]) * rs_s[row] * lw + lb);
            }
    }
    __syncthreads();

    // GEMM2: g = h @ w1 + b1, GELU -> H
    v4f acc2[2][6];
#pragma unroll
    for (int m = 0; m < 2; ++m)
#pragma unroll
        for (int n = 0; n < 6; ++n) acc2[m][n] = (v4f){0.f,0.f,0.f,0.f};
#pragma unroll
    for (int kk = 0; kk < 6; ++kk) {
        v8bf a0 = *(const v8bf*)&Abf[qi][kk * 32 + g * 8];
        v8bf a1 = *(const v8bf*)&Abf[16 + qi][kk * 32 + g * 8];
#pragma unroll
        for (int n = 0; n < 6; ++n) {
            v8bf bfr = *(const v8bf*)(w1T + (size_t)(w * 96 + n * 16 + qi) * C_ + kk * 32 + g * 8);
            acc2[0][n] = MFMA16(a0, bfr, acc2[0][n]);
            acc2[1][n] = MFMA16(a1, bfr, acc2[1][n]);
        }
    }
#pragma unroll
    for (int n = 0; n < 6; ++n) {
        int col = w * 96 + n * 16 + qi;
        float bb = b1[col];
#pragma unroll
        for (int m = 0; m < 2; ++m)
#pragma unroll
            for (int r = 0; r < 4; ++r)
                H[m * 16 + g * 4 + r][col] = (__bf16)gelu_erf(acc2[m][n][r] + bb);
    }
    __syncthreads();

    // GEMM3: f = g @ w2 + b2; out = o + f
    v4f acc3[2][3];
#pragma unroll
    for (int m = 0; m < 2; ++m)
#pragma unroll
        for (int n = 0; n < 3; ++n) acc3[m][n] = (v4f){0.f,0.f,0.f,0.f};
#pragma unroll
    for (int kk = 0; kk < 12; ++kk) {
        v8bf a0 = *(const v8bf*)&H[qi][kk * 32 + g * 8];
        v8bf a1 = *(const v8bf*)&H[16 + qi][kk * 32 + g * 8];
#pragma unroll
        for (int n = 0; n < 3; ++n) {
            v8bf bfr = *(const v8bf*)(w2T + (size_t)(w * 48 + n * 16 + qi) * MLPH_ + kk * 32 + g * 8);
            acc3[0][n] = MFMA16(a0, bfr, acc3[0][n]);
            acc3[1][n] = MFMA16(a1, bfr, acc3[1][n]);
        }
    }
#pragma unroll
    for (int n = 0; n < 3; ++n) {
        int col = w * 48 + n * 16 + qi;
        float bb = b2[col];
#pragma unroll
        for (int m = 0; m < 2; ++m)
#pragma unroll
            for (int r = 0; r < 4; ++r)
                out[(row0 + m * 16 + g * 4 + r) * C_ + col] = acc1[m][n][r] + acc3[m][n][r] + bb;
    }
}

extern "C" void kernel_launch(void* const* d_in, const int* in_sizes, int n_in,
                              void* d_out, int out_size, void* d_ws, size_t ws_size,
                              hipStream_t stream) {
    const float* x    = (const float*)d_in[0];
    const float* lnqw = (const float*)d_in[1];
    const float* lnqb = (const float*)d_in[2];
    const float* lnkw = (const float*)d_in[3];
    const float* lnkb = (const float*)d_in[4];
    const float* wq   = (const float*)d_in[5];
    const float* bq   = (const float*)d_in[6];
    const float* wk   = (const float*)d_in[7];
    const float* bk   = (const float*)d_in[8];
    const float* wv   = (const float*)d_in[9];
    const float* bv   = (const float*)d_in[10];
    const float* wo   = (const float*)d_in[11];
    const float* bo   = (const float*)d_in[12];
    const float* ln2w = (const float*)d_in[13];
    const float* ln2b = (const float*)d_in[14];
    const float* w1   = (const float*)d_in[15];
    const float* b1   = (const float*)d_in[16];
    const float* w2   = (const float*)d_in[17];
    const float* b2   = (const float*)d_in[18];

    char* w0 = (char*)d_ws;
    const size_t QB  = (size_t)B_ * N_ * C_ * 2;       // 7,077,888
    const size_t KVB = (size_t)B_ * TKP_ * C_ * 2;     // 1,794,048
    const size_t POB = (size_t)4 * B_ * N_ * C_ * 2;   // 28,311,552 (4 bf16 splits)
    __bf16* qb  = (__bf16*)(w0);
    __bf16* kcb = (__bf16*)(w0 + QB);
    __bf16* vtr = (__bf16*)(w0 + QB + KVB);
    __bf16* po  = (__bf16*)(w0 + QB + 2 * KVB);
    float*  psb = (float*) (w0 + QB + 2 * KVB + POB);    // 8*6*N f32
    float*  kp    = psb + (size_t)8 * 6 * N_;            // 96*192
    float*  vp    = kp + 96 * C_;                        // 96*192
    float*  part  = vp + 96 * C_;                        // 144*192
    float*  meanx = part + 144 * C_;
    char* wbase = (char*)(meanx + 192 + 32);
    wbase = (char*)(((uintptr_t)wbase + 255) & ~(uintptr_t)255);
    __bf16* wqT = (__bf16*)(wbase);
    __bf16* wkT = wqT + 36864;
    __bf16* wvT = wkT + 36864;
    __bf16* woT = wvT + 36864;
    __bf16* w1T = woT + 36864;
    __bf16* w2T = w1T + 73728;

    hipLaunchKernelGGL(k_pre1, dim3(432), dim3(256), 0, stream,
                       wq, wk, wv, wo, w1, w2, wqT, wkT, wvT, woT, w1T, w2T, x, part);
    hipLaunchKernelGGL(k_pre2, dim3(145), dim3(256), 0, stream,
                       x, lnkw, lnkb, wkT, bk, wvT, bv, kcb, vtr, part, meanx);
    hipLaunchKernelGGL(k_pre3, dim3(672), dim3(256), 0, stream,
                       x, lnqw, lnqb, wqT, bq, qb, kcb, vtr, kp, vp);
    hipLaunchKernelGGL(k_memfin, dim3(32), dim3(192), 0, stream, meanx, kp, vp, kcb, vtr);
    hipLaunchKernelGGL(k_attn, dim3(144, 6, 8), dim3(64), 0, stream,
                       qb, kcb, vtr, po, psb);
    hipLaunchKernelGGL(k_post, dim3(576), dim3(256), 0, stream,
                       po, psb, woT, bo, ln2w, ln2b, w1T, b1, w2T, b2, (float*)d_out);
}